// Round 3
// baseline (1531.543 us; speedup 1.0000x reference)
//
#include <hip/hip_runtime.h>

#define N_NODES 100000
#define N_EDGES 1600000
#define BN_EPS 1e-5f
#define NB 782        // ceil(100000/128) buckets of 128 nodes
#define CH 4096       // edges per binning block

typedef short short8 __attribute__((ext_vector_type(8)));
typedef float floatx4 __attribute__((ext_vector_type(4)));

__device__ __forceinline__ unsigned short f2bf(float f) {
    unsigned int u = __float_as_uint(f);
    unsigned int r = (u + 0x7fffu + ((u >> 16) & 1u)) >> 16;  // RNE
    return (unsigned short)r;
}

// ---------------- degree count ----------------
__global__ void k_deg(const int* __restrict__ col, int* __restrict__ deg, int E) {
    int e = blockIdx.x * 256 + threadIdx.x;
    if (e < E) atomicAdd(&deg[col[e]], 1);
}

// ---------------- dinv = rsqrt(deg + 1 self loop) ----------------
__global__ void k_dinv(const int* __restrict__ deg, float* __restrict__ dinv, int n) {
    int i = blockIdx.x * 256 + threadIdx.x;
    if (i < n) dinv[i] = rsqrtf((float)(deg[i] + 1));
}

// ---------------- per-bucket edge counts (sum of deg over 128-node range) ----------------
__global__ void k_bsum(const int* __restrict__ deg, int* __restrict__ bsum, int n) {
    __shared__ int sd[128];
    int b = blockIdx.x, t = threadIdx.x;
    int i = b * 128 + t;
    sd[t] = (i < n) ? deg[i] : 0;
    __syncthreads();
    for (int o = 64; o > 0; o >>= 1) {
        if (t < o) sd[t] += sd[t + o];
        __syncthreads();
    }
    if (t == 0) bsum[b] = sd[0];
}

// ---------------- exclusive scan of bucket counts (1 block) ----------------
__global__ void k_bscan(const int* __restrict__ bsum, int* __restrict__ boff,
                        int* __restrict__ bcur) {
    __shared__ int sd[1024];
    int t = threadIdx.x;
    int v = (t < NB) ? bsum[t] : 0;
    sd[t] = v;
    __syncthreads();
    for (int o = 1; o < 1024; o <<= 1) {
        int x = (t >= o) ? sd[t - o] : 0;
        __syncthreads();
        sd[t] += x;
        __syncthreads();
    }
    int ex = sd[t] - v;
    if (t <= NB) boff[t] = ex;   // boff[NB] == E
    if (t < NB) bcur[t] = ex;
}

// ---------------- LDS-staged binning: edges -> bucket-grouped code words ----------------
// code = src | (local_dst << 17)
__global__ __launch_bounds__(256) void k_bin(const int* __restrict__ ei,
                                             int* __restrict__ bcur,
                                             unsigned int* __restrict__ binned, int E) {
    __shared__ int hist[1024];
    __shared__ int base[1024];
    __shared__ int gbase[1024];
    __shared__ int warr[256];
    __shared__ unsigned int stage[CH];
    __shared__ unsigned short stb[CH];
    int tid = threadIdx.x;
    int e0 = blockIdx.x * CH;
    int cn = min(CH, E - e0);

    for (int i = tid; i < 1024; i += 256) hist[i] = 0;
    __syncthreads();

    unsigned int mycode[16];
    short myb[16], myslot[16];
    #pragma unroll
    for (int j = 0; j < 16; j++) {
        int idx = j * 256 + tid;
        if (idx < cn) {
            int e = e0 + idx;
            int src = ei[e];
            int dst = ei[E + e];
            int b = dst >> 7;
            mycode[j] = (unsigned int)src | ((unsigned int)(dst & 127) << 17);
            myb[j] = (short)b;
            myslot[j] = (short)atomicAdd(&hist[b], 1);
        } else myb[j] = -1;
    }
    __syncthreads();

    // exclusive scan of hist[1024] with 256 threads (4 per thread + Hillis-Steele)
    int h0 = hist[tid * 4], h1 = hist[tid * 4 + 1], h2 = hist[tid * 4 + 2], h3 = hist[tid * 4 + 3];
    int t4 = h0 + h1 + h2 + h3;
    warr[tid] = t4;
    __syncthreads();
    for (int o = 1; o < 256; o <<= 1) {
        int x = (tid >= o) ? warr[tid - o] : 0;
        __syncthreads();
        warr[tid] += x;
        __syncthreads();
    }
    int ex = warr[tid] - t4;
    base[tid * 4] = ex;
    base[tid * 4 + 1] = ex + h0;
    base[tid * 4 + 2] = ex + h0 + h1;
    base[tid * 4 + 3] = ex + h0 + h1 + h2;
    __syncthreads();

    // place into staged, bucket-grouped order
    #pragma unroll
    for (int j = 0; j < 16; j++) {
        if (myb[j] >= 0) {
            int p = base[myb[j]] + myslot[j];
            stage[p] = mycode[j];
            stb[p] = (unsigned short)myb[j];
        }
    }
    // reserve global regions per bucket
    for (int b = tid; b < NB; b += 256) {
        int c = hist[b];
        if (c) gbase[b] = atomicAdd(&bcur[b], c);
    }
    __syncthreads();
    // coalesced-ish copyout (consecutive i in a bucket -> consecutive global)
    for (int i = tid; i < cn; i += 256) {
        int b = stb[i];
        binned[gbase[b] + (i - base[b])] = stage[i];
    }
}

// ---------------- W f32 -> bf16 ----------------
__global__ void k_wcvt(const float* __restrict__ Wf, unsigned short* __restrict__ Wb) {
    int i = blockIdx.x * 256 + threadIdx.x;
    if (i < 128 * 128) Wb[i] = f2bf(Wf[i]);
}

// ---------------- GEMM h = x @ W^T via bf16 MFMA, h stored as bf16 ----------------
__global__ __launch_bounds__(256) void k_gemm(const float* __restrict__ x,
                                              const unsigned short* __restrict__ Wb,
                                              unsigned short* __restrict__ hb, int n) {
    int w = threadIdx.x >> 6;
    int l = threadIdx.x & 63;
    int rowbase = blockIdx.x * 256 + w * 64;
    int r16 = l & 15;
    int kg = l >> 4;

    short8 a[4][4];
    #pragma unroll
    for (int m = 0; m < 4; m++) {
        int row = rowbase + m * 16 + r16;
        int rca = min(row, n - 1);
        const float* base = x + rca * 128;
        #pragma unroll
        for (int q = 0; q < 4; q++) {
            const float4* xp = (const float4*)(base + q * 32 + kg * 8);
            float4 lo = xp[0], hi = xp[1];
            short8 af;
            af[0] = (short)f2bf(lo.x); af[1] = (short)f2bf(lo.y);
            af[2] = (short)f2bf(lo.z); af[3] = (short)f2bf(lo.w);
            af[4] = (short)f2bf(hi.x); af[5] = (short)f2bf(hi.y);
            af[6] = (short)f2bf(hi.z); af[7] = (short)f2bf(hi.w);
            a[m][q] = af;
        }
    }
    for (int t = 0; t < 8; t++) {
        int col = t * 16 + r16;
        short8 b[4];
        #pragma unroll
        for (int q = 0; q < 4; q++)
            b[q] = *(const short8*)(Wb + col * 128 + q * 32 + kg * 8);

        floatx4 acc[4] = {};
        #pragma unroll
        for (int m = 0; m < 4; m++)
            #pragma unroll
            for (int q = 0; q < 4; q++)
                acc[m] = __builtin_amdgcn_mfma_f32_16x16x32_bf16(a[m][q], b[q], acc[m], 0, 0, 0);

        #pragma unroll
        for (int m = 0; m < 4; m++) {
            #pragma unroll
            for (int r = 0; r < 4; r++) {
                int row = rowbase + m * 16 + kg * 4 + r;
                if (row < n) hb[row * 128 + col] = f2bf(acc[m][r]);
            }
        }
    }
}

// ---------------- bucket aggregation: block per 128-node bucket, LDS f32 tile ----------------
__global__ __launch_bounds__(512) void k_bagg(const unsigned int* __restrict__ hp,
        const float* __restrict__ dinv, const int* __restrict__ boff,
        const unsigned int* __restrict__ binned, float* __restrict__ out,
        float* __restrict__ sums, float* __restrict__ sumsq, int n) {
    __shared__ float tile[128][128];   // 64 KB
    __shared__ float dl[128];
    __shared__ float ps[8][128];
    __shared__ float pq[8][128];
    int w = threadIdx.x >> 6;   // 0..7
    int l = threadIdx.x & 63;
    int b = blockIdx.x;
    int nb0 = b * 128;
    int nr = min(128, n - nb0);

    // init with self-loop contribution h[i] * dinv[i]^2
    for (int r = w; r < nr; r += 8) {
        int i = nb0 + r;
        float di = dinv[i];
        unsigned int sv = hp[i * 64 + l];
        float sn = di * di;
        tile[r][2 * l]     = __uint_as_float(sv << 16) * sn;
        tile[r][2 * l + 1] = __uint_as_float(sv & 0xffff0000u) * sn;
        if (l == 0) dl[r] = di;
    }
    __syncthreads();

    int e0 = boff[b];
    int cnt = boff[b + 1] - e0;
    for (int base = w * 64; base < cnt; base += 512) {
        int rem = min(cnt - base, 64);
        unsigned int code = 0;
        float nrm = 0.f;
        if (l < rem) {
            code = binned[e0 + base + l];
            int src = code & 0x1FFFF;
            nrm = dinv[src] * dl[code >> 17];
        }
        for (int e = 0; e < rem; e++) {
            unsigned int ce = __shfl(code, e);
            float ne = __shfl(nrm, e);
            int src = ce & 0x1FFFF;
            int ldst = ce >> 17;
            unsigned int hv = hp[src * 64 + l];
            atomicAdd(&tile[ldst][2 * l],     ne * __uint_as_float(hv << 16));
            atomicAdd(&tile[ldst][2 * l + 1], ne * __uint_as_float(hv & 0xffff0000u));
        }
    }
    __syncthreads();

    // writeout + per-column partial BN stats
    float s0 = 0, s1 = 0, q0 = 0, q1 = 0;
    for (int r = w; r < nr; r += 8) {
        float v0 = tile[r][2 * l], v1 = tile[r][2 * l + 1];
        ((float2*)out)[(nb0 + r) * 64 + l] = make_float2(v0, v1);
        s0 += v0; s1 += v1; q0 += v0 * v0; q1 += v1 * v1;
    }
    ps[w][2 * l] = s0; ps[w][2 * l + 1] = s1;
    pq[w][2 * l] = q0; pq[w][2 * l + 1] = q1;
    __syncthreads();
    if (threadIdx.x < 128) {
        float s = 0, q = 0;
        #pragma unroll
        for (int ww = 0; ww < 8; ww++) { s += ps[ww][threadIdx.x]; q += pq[ww][threadIdx.x]; }
        atomicAdd(&sums[threadIdx.x], s);
        atomicAdd(&sumsq[threadIdx.x], q);
    }
}

// ---------------- BN normalize + ReLU (in place on out) ----------------
__global__ void k_bn(float* __restrict__ out, const float* __restrict__ sums,
                     const float* __restrict__ sumsq, const float* __restrict__ gamma,
                     const float* __restrict__ beta, int n) {
    int idx = blockIdx.x * 256 + threadIdx.x;
    int total = n * 32;
    if (idx >= total) return;
    int c0 = (idx & 31) * 4;
    float invN = 1.0f / (float)n;
    float4 v = ((const float4*)out)[idx];
    float r[4] = {v.x, v.y, v.z, v.w};
    #pragma unroll
    for (int j = 0; j < 4; j++) {
        int c = c0 + j;
        float mean = sums[c] * invN;
        float var = sumsq[c] * invN - mean * mean;
        float scale = rsqrtf(var + BN_EPS) * gamma[c];
        float o = (r[j] - mean) * scale + beta[c];
        r[j] = fmaxf(o, 0.0f);
    }
    ((float4*)out)[idx] = make_float4(r[0], r[1], r[2], r[3]);
}

extern "C" void kernel_launch(void* const* d_in, const int* in_sizes, int n_in,
                              void* d_out, int out_size, void* d_ws, size_t ws_size,
                              hipStream_t stream) {
    const float* x     = (const float*)d_in[0];
    const int*   ei    = (const int*)d_in[1];     // [2][E]
    const float* W     = (const float*)d_in[2];
    // d_in[3] = b : cancels exactly under training-mode BatchNorm -> unused
    const float* gamma = (const float*)d_in[4];
    const float* beta  = (const float*)d_in[5];
    float* out = (float*)d_out;

    const int n = N_NODES, E = N_EDGES;

    // workspace layout
    unsigned short* hb = (unsigned short*)d_ws;        // 12.8M bf16 (25.6 MB)
    float* dinv   = (float*)(hb + 12800000);           // 100k f32
    int*   deg    = (int*)(dinv + 100000);             // 100k
    int*   bsum   = deg + 100000;                      // NB
    int*   boff   = bsum + NB;                         // NB+1
    int*   bcur   = boff + NB + 1;                     // NB
    unsigned int* binned = (unsigned int*)(bcur + NB); // 1.6M
    float* sums   = (float*)(binned + N_EDGES);        // 128
    float* sumsq  = sums + 128;                        // 128
    unsigned short* Wb = (unsigned short*)(sumsq + 128); // 16384 bf16

    hipMemsetAsync(deg, 0, n * sizeof(int), stream);
    hipMemsetAsync(sums, 0, 256 * sizeof(float), stream);

    k_deg<<<(E + 255) / 256, 256, 0, stream>>>(ei + E, deg, E);
    k_dinv<<<(n + 255) / 256, 256, 0, stream>>>(deg, dinv, n);
    k_bsum<<<NB, 128, 0, stream>>>(deg, bsum, n);
    k_bscan<<<1, 1024, 0, stream>>>(bsum, boff, bcur);
    k_bin<<<(E + CH - 1) / CH, 256, 0, stream>>>(ei, bcur, binned, E);

    k_wcvt<<<64, 256, 0, stream>>>(W, Wb);
    k_gemm<<<(n + 255) / 256, 256, 0, stream>>>(x, Wb, hb, n);

    k_bagg<<<NB, 512, 0, stream>>>((const unsigned int*)hb, dinv, boff, binned,
                                   out, sums, sumsq, n);

    k_bn<<<(n * 32 + 255) / 256, 256, 0, stream>>>(out, sums, sumsq, gamma, beta, n);
}

// Round 4
// 272.053 us; speedup vs baseline: 5.6296x; 5.6296x over previous
//
#include <hip/hip_runtime.h>

#define N_NODES 100000
#define N_EDGES 1600000
#define BN_EPS 1e-5f
#define NB 782        // ceil(100000/128) buckets of 128 nodes
#define CH 4096       // edges per binning block

typedef short short8 __attribute__((ext_vector_type(8)));
typedef float floatx4 __attribute__((ext_vector_type(4)));

__device__ __forceinline__ unsigned short f2bf(float f) {
    unsigned int u = __float_as_uint(f);
    unsigned int r = (u + 0x7fffu + ((u >> 16) & 1u)) >> 16;  // RNE
    return (unsigned short)r;
}
__device__ __forceinline__ float bflo(unsigned int v) { return __uint_as_float(v << 16); }
__device__ __forceinline__ float bfhi(unsigned int v) { return __uint_as_float(v & 0xffff0000u); }

// ---------------- degree count ----------------
__global__ void k_deg(const int* __restrict__ col, int* __restrict__ deg, int E) {
    int e = blockIdx.x * 256 + threadIdx.x;
    if (e < E) atomicAdd(&deg[col[e]], 1);
}

// ---------------- dinv = rsqrt(deg + 1 self loop) ----------------
__global__ void k_dinv(const int* __restrict__ deg, float* __restrict__ dinv, int n) {
    int i = blockIdx.x * 256 + threadIdx.x;
    if (i < n) dinv[i] = rsqrtf((float)(deg[i] + 1));
}

// ---------------- scan part 1: per-block sums ----------------
__global__ void k_part(const int* __restrict__ deg, int* __restrict__ parts, int n) {
    __shared__ int sd[256];
    int tid = threadIdx.x;
    int idx = blockIdx.x * 256 + tid;
    sd[tid] = (idx < n) ? deg[idx] : 0;
    __syncthreads();
    for (int o = 128; o > 0; o >>= 1) {
        if (tid < o) sd[tid] += sd[tid + o];
        __syncthreads();
    }
    if (tid == 0) parts[blockIdx.x] = sd[0];
}

// ---------------- scan part 2: scan the partials (1 block) ----------------
__global__ void k_top(const int* __restrict__ parts, int* __restrict__ pscan, int np) {
    __shared__ int sd[256];
    __shared__ int run_s;
    int tid = threadIdx.x;
    if (tid == 0) run_s = 0;
    __syncthreads();
    for (int base = 0; base < np; base += 256) {
        int idx = base + tid;
        int v = (idx < np) ? parts[idx] : 0;
        sd[tid] = v;
        __syncthreads();
        for (int o = 1; o < 256; o <<= 1) {
            int t = (tid >= o) ? sd[tid - o] : 0;
            __syncthreads();
            sd[tid] += t;
            __syncthreads();
        }
        int brun = run_s;
        if (idx < np) pscan[idx] = brun + sd[tid] - v;  // exclusive
        __syncthreads();
        if (tid == 0) run_s += sd[255];
        __syncthreads();
    }
}

// ---------------- scan part 3: per-element exclusive offsets + bucket cursors ----------------
__global__ void k_apply(const int* __restrict__ deg, const int* __restrict__ pscan,
                        int* __restrict__ offs, int* __restrict__ bcur, int n) {
    __shared__ int sd[256];
    int tid = threadIdx.x;
    int idx = blockIdx.x * 256 + tid;
    int v = (idx < n) ? deg[idx] : 0;
    sd[tid] = v;
    __syncthreads();
    for (int o = 1; o < 256; o <<= 1) {
        int t = (tid >= o) ? sd[tid - o] : 0;
        __syncthreads();
        sd[tid] += t;
        __syncthreads();
    }
    if (idx < n) {
        int ex = pscan[blockIdx.x] + sd[tid] - v;
        offs[idx] = ex;
        if ((idx & 127) == 0) bcur[idx >> 7] = ex;   // bucket start = node-scan at boundary
    }
}

// ---------------- LDS-staged binning: edges -> bucket-grouped code words ----------------
// code = src | (local_dst << 17); bucket regions in `binned` == [offs[128b], offs[128(b+1)])
__global__ __launch_bounds__(256) void k_bin(const int* __restrict__ ei,
                                             int* __restrict__ bcur,
                                             unsigned int* __restrict__ binned, int E) {
    __shared__ int hist[1024];
    __shared__ int base[1024];
    __shared__ int gbase[1024];
    __shared__ int warr[256];
    __shared__ unsigned int stage[CH];
    __shared__ unsigned short stb[CH];
    int tid = threadIdx.x;
    int e0 = blockIdx.x * CH;
    int cn = min(CH, E - e0);

    for (int i = tid; i < 1024; i += 256) hist[i] = 0;
    __syncthreads();

    unsigned int mycode[16];
    short myb[16], myslot[16];
    #pragma unroll
    for (int j = 0; j < 16; j++) {
        int idx = j * 256 + tid;
        if (idx < cn) {
            int e = e0 + idx;
            int src = ei[e];
            int dst = ei[E + e];
            int b = dst >> 7;
            mycode[j] = (unsigned int)src | ((unsigned int)(dst & 127) << 17);
            myb[j] = (short)b;
            myslot[j] = (short)atomicAdd(&hist[b], 1);
        } else myb[j] = -1;
    }
    __syncthreads();

    int h0 = hist[tid * 4], h1 = hist[tid * 4 + 1], h2 = hist[tid * 4 + 2], h3 = hist[tid * 4 + 3];
    int t4 = h0 + h1 + h2 + h3;
    warr[tid] = t4;
    __syncthreads();
    for (int o = 1; o < 256; o <<= 1) {
        int x = (tid >= o) ? warr[tid - o] : 0;
        __syncthreads();
        warr[tid] += x;
        __syncthreads();
    }
    int ex = warr[tid] - t4;
    base[tid * 4] = ex;
    base[tid * 4 + 1] = ex + h0;
    base[tid * 4 + 2] = ex + h0 + h1;
    base[tid * 4 + 3] = ex + h0 + h1 + h2;
    __syncthreads();

    #pragma unroll
    for (int j = 0; j < 16; j++) {
        if (myb[j] >= 0) {
            int p = base[myb[j]] + myslot[j];
            stage[p] = mycode[j];
            stb[p] = (unsigned short)myb[j];
        }
    }
    for (int b = tid; b < NB; b += 256) {
        int c = hist[b];
        if (c) gbase[b] = atomicAdd(&bcur[b], c);
    }
    __syncthreads();
    for (int i = tid; i < cn; i += 256) {
        int b = stb[i];
        binned[gbase[b] + (i - base[b])] = stage[i];
    }
}

// ---------------- per-bucket exact CSR scatter (writes stay in one 8KB L2 region) ----------------
__global__ __launch_bounds__(256) void k_sort(const unsigned int* __restrict__ binned,
                                              const int* __restrict__ offs,
                                              int* __restrict__ csr, int n, int E) {
    __shared__ int lcur[128];
    int b = blockIdx.x, t = threadIdx.x;
    int nb0 = b * 128;
    if (t < 128 && nb0 + t < n) lcur[t] = offs[nb0 + t];
    __syncthreads();
    int e0 = offs[nb0];
    int e1 = (b == NB - 1) ? E : offs[nb0 + 128];
    int cnt = e1 - e0;
    for (int i = t; i < cnt; i += 256) {
        unsigned int code = binned[e0 + i];
        int pos = atomicAdd(&lcur[code >> 17], 1);
        csr[pos] = (int)(code & 0x1FFFF);
    }
}

// ---------------- W f32 -> bf16 ----------------
__global__ void k_wcvt(const float* __restrict__ Wf, unsigned short* __restrict__ Wb) {
    int i = blockIdx.x * 256 + threadIdx.x;
    if (i < 128 * 128) Wb[i] = f2bf(Wf[i]);
}

// ---------------- GEMM h = x @ W^T via bf16 MFMA, h stored as bf16 ----------------
__global__ __launch_bounds__(256) void k_gemm(const float* __restrict__ x,
                                              const unsigned short* __restrict__ Wb,
                                              unsigned short* __restrict__ hb, int n) {
    int w = threadIdx.x >> 6;
    int l = threadIdx.x & 63;
    int rowbase = blockIdx.x * 256 + w * 64;
    int r16 = l & 15;
    int kg = l >> 4;

    short8 a[4][4];
    #pragma unroll
    for (int m = 0; m < 4; m++) {
        int row = rowbase + m * 16 + r16;
        int rca = min(row, n - 1);
        const float* base = x + rca * 128;
        #pragma unroll
        for (int q = 0; q < 4; q++) {
            const float4* xp = (const float4*)(base + q * 32 + kg * 8);
            float4 lo = xp[0], hi = xp[1];
            short8 af;
            af[0] = (short)f2bf(lo.x); af[1] = (short)f2bf(lo.y);
            af[2] = (short)f2bf(lo.z); af[3] = (short)f2bf(lo.w);
            af[4] = (short)f2bf(hi.x); af[5] = (short)f2bf(hi.y);
            af[6] = (short)f2bf(hi.z); af[7] = (short)f2bf(hi.w);
            a[m][q] = af;
        }
    }
    for (int t = 0; t < 8; t++) {
        int col = t * 16 + r16;
        short8 b[4];
        #pragma unroll
        for (int q = 0; q < 4; q++)
            b[q] = *(const short8*)(Wb + col * 128 + q * 32 + kg * 8);

        floatx4 acc[4] = {};
        #pragma unroll
        for (int m = 0; m < 4; m++)
            #pragma unroll
            for (int q = 0; q < 4; q++)
                acc[m] = __builtin_amdgcn_mfma_f32_16x16x32_bf16(a[m][q], b[q], acc[m], 0, 0, 0);

        #pragma unroll
        for (int m = 0; m < 4; m++) {
            #pragma unroll
            for (int r = 0; r < 4; r++) {
                int row = rowbase + m * 16 + kg * 4 + r;
                if (row < n) hb[row * 128 + col] = f2bf(acc[m][r]);
            }
        }
    }
}

// ---------------- aggregation: one wave per node, register accumulation, 4x MLP ----------------
__global__ void k_agg(const unsigned int* __restrict__ hp, const float* __restrict__ dinv,
                      const int* __restrict__ offs, const int* __restrict__ deg,
                      const int* __restrict__ csr, float* __restrict__ out, int n) {
    int w = threadIdx.x >> 6;
    int l = threadIdx.x & 63;
    int i = blockIdx.x * 4 + w;
    if (i >= n) return;
    float di = dinv[i];
    unsigned int sv = hp[i * 64 + l];
    float sn = di * di;
    float ax = bflo(sv) * sn;
    float ay = bfhi(sv) * sn;
    int s0 = offs[i];
    int cnt = deg[i];
    for (int base = 0; base < cnt; base += 64) {
        int rem = min(cnt - base, 64);
        int   myidx = (l < rem) ? csr[s0 + base + l] : 0;
        float mydi  = (l < rem) ? dinv[myidx] : 0.0f;
        int e = 0;
        for (; e + 3 < rem; e += 4) {
            int sA = __shfl(myidx, e),     sB = __shfl(myidx, e + 1);
            int sC = __shfl(myidx, e + 2), sD = __shfl(myidx, e + 3);
            float nA = di * __shfl(mydi, e),     nB = di * __shfl(mydi, e + 1);
            float nC = di * __shfl(mydi, e + 2), nD = di * __shfl(mydi, e + 3);
            unsigned int hA = hp[sA * 64 + l];
            unsigned int hB = hp[sB * 64 + l];
            unsigned int hC = hp[sC * 64 + l];
            unsigned int hD = hp[sD * 64 + l];
            ax += nA * bflo(hA); ay += nA * bfhi(hA);
            ax += nB * bflo(hB); ay += nB * bfhi(hB);
            ax += nC * bflo(hC); ay += nC * bfhi(hC);
            ax += nD * bflo(hD); ay += nD * bfhi(hD);
        }
        for (; e < rem; e++) {
            int src = __shfl(myidx, e);
            float nrm = di * __shfl(mydi, e);
            unsigned int hv = hp[src * 64 + l];
            ax += nrm * bflo(hv);
            ay += nrm * bfhi(hv);
        }
    }
    ((float2*)out)[i * 64 + l] = make_float2(ax, ay);
}

// ---------------- BN stats: per-column sum & sumsq ----------------
__global__ void k_stats(const float* __restrict__ out, float* __restrict__ sums,
                        float* __restrict__ sumsq, int n) {
    int tid = threadIdx.x;
    int c = tid & 127;
    int rh = tid >> 7;  // 0..1
    float s = 0.f, s2 = 0.f;
    for (int r = blockIdx.x * 2 + rh; r < n; r += gridDim.x * 2) {
        float v = out[r * 128 + c];
        s += v;
        s2 += v * v;
    }
    __shared__ float ls[256], ls2[256];
    ls[tid] = s; ls2[tid] = s2;
    __syncthreads();
    if (tid < 128) {
        s = ls[tid] + ls[tid + 128];
        s2 = ls2[tid] + ls2[tid + 128];
        atomicAdd(&sums[c], s);
        atomicAdd(&sumsq[c], s2);
    }
}

// ---------------- BN normalize + ReLU (in place on out) ----------------
__global__ void k_bn(float* __restrict__ out, const float* __restrict__ sums,
                     const float* __restrict__ sumsq, const float* __restrict__ gamma,
                     const float* __restrict__ beta, int n) {
    int idx = blockIdx.x * 256 + threadIdx.x;
    int total = n * 32;
    if (idx >= total) return;
    int c0 = (idx & 31) * 4;
    float invN = 1.0f / (float)n;
    float4 v = ((const float4*)out)[idx];
    float r[4] = {v.x, v.y, v.z, v.w};
    #pragma unroll
    for (int j = 0; j < 4; j++) {
        int c = c0 + j;
        float mean = sums[c] * invN;
        float var = sumsq[c] * invN - mean * mean;
        float scale = rsqrtf(var + BN_EPS) * gamma[c];
        float o = (r[j] - mean) * scale + beta[c];
        r[j] = fmaxf(o, 0.0f);
    }
    ((float4*)out)[idx] = make_float4(r[0], r[1], r[2], r[3]);
}

extern "C" void kernel_launch(void* const* d_in, const int* in_sizes, int n_in,
                              void* d_out, int out_size, void* d_ws, size_t ws_size,
                              hipStream_t stream) {
    const float* x     = (const float*)d_in[0];
    const int*   ei    = (const int*)d_in[1];     // [2][E]
    const float* W     = (const float*)d_in[2];
    // d_in[3] = b : cancels exactly under training-mode BatchNorm -> unused
    const float* gamma = (const float*)d_in[4];
    const float* beta  = (const float*)d_in[5];
    float* out = (float*)d_out;

    const int n = N_NODES, E = N_EDGES;

    // workspace layout
    unsigned short* hb = (unsigned short*)d_ws;        // 12.8M bf16 (25.6 MB)
    float* dinv   = (float*)(hb + 12800000);           // 100k f32
    int*   deg    = (int*)(dinv + 100000);             // 100k
    int*   offs   = deg + 100000;                      // 100k
    int*   bcur   = offs + 100000;                     // NB
    unsigned int* binned = (unsigned int*)(bcur + NB); // 1.6M
    int*   csr    = (int*)(binned + N_EDGES);          // 1.6M
    int*   parts  = csr + N_EDGES;                     // 512
    int*   pscan  = parts + 512;                       // 512
    float* sums   = (float*)(pscan + 512);             // 128
    float* sumsq  = sums + 128;                        // 128
    unsigned short* Wb = (unsigned short*)(sumsq + 128); // 16384 bf16

    const int nb256 = (n + 255) / 256;                 // 391

    hipMemsetAsync(deg, 0, n * sizeof(int), stream);
    hipMemsetAsync(sums, 0, 256 * sizeof(float), stream);

    k_deg<<<(E + 255) / 256, 256, 0, stream>>>(ei + E, deg, E);
    k_dinv<<<(n + 255) / 256, 256, 0, stream>>>(deg, dinv, n);
    k_part<<<nb256, 256, 0, stream>>>(deg, parts, n);
    k_top<<<1, 256, 0, stream>>>(parts, pscan, nb256);
    k_apply<<<nb256, 256, 0, stream>>>(deg, pscan, offs, bcur, n);
    k_bin<<<(E + CH - 1) / CH, 256, 0, stream>>>(ei, bcur, binned, E);
    k_sort<<<NB, 256, 0, stream>>>(binned, offs, csr, n, E);

    k_wcvt<<<64, 256, 0, stream>>>(W, Wb);
    k_gemm<<<(n + 255) / 256, 256, 0, stream>>>(x, Wb, hb, n);

    k_agg<<<(n + 3) / 4, 256, 0, stream>>>((const unsigned int*)hb, dinv, offs, deg, csr, out, n);

    k_stats<<<512, 256, 0, stream>>>(out, sums, sumsq, n);
    k_bn<<<(n * 32 + 255) / 256, 256, 0, stream>>>(out, sums, sumsq, gamma, beta, n);
}

// Round 5
// 194.069 us; speedup vs baseline: 7.8917x; 1.4018x over previous
//
#include <hip/hip_runtime.h>

#define N_NODES 100000
#define N_EDGES 1600000
#define BN_EPS 1e-5f
#define NB 782        // ceil(100000/128) buckets of 128 nodes
#define CAP 2688      // fixed bucket capacity (mean 2048 + 14 sigma)
#define CH 4096       // edges per binning block

typedef short short8 __attribute__((ext_vector_type(8)));
typedef float floatx4 __attribute__((ext_vector_type(4)));

__device__ __forceinline__ unsigned short f2bf(float f) {
    unsigned int u = __float_as_uint(f);
    unsigned int r = (u + 0x7fffu + ((u >> 16) & 1u)) >> 16;  // RNE
    return (unsigned short)r;
}
__device__ __forceinline__ float bflo(unsigned int v) { return __uint_as_float(v << 16); }
__device__ __forceinline__ float bfhi(unsigned int v) { return __uint_as_float(v & 0xffff0000u); }

// ---------------- init bucket cursors to fixed-capacity region starts ----------------
__global__ void k_initb(int* __restrict__ bcur) {
    int i = blockIdx.x * 256 + threadIdx.x;
    if (i < NB) bcur[i] = i * CAP;
}

// ---------------- LDS-staged binning: edges -> bucket-grouped code words ----------------
// code = src | (local_dst << 17); bucket b's region = [b*CAP, bcur[b])
__global__ __launch_bounds__(256) void k_bin(const int* __restrict__ ei,
                                             int* __restrict__ bcur,
                                             unsigned int* __restrict__ binned, int E) {
    __shared__ int hist[1024];
    __shared__ int base[1024];
    __shared__ int gbase[1024];
    __shared__ int warr[256];
    __shared__ unsigned int stage[CH];
    __shared__ unsigned short stb[CH];
    int tid = threadIdx.x;
    int e0 = blockIdx.x * CH;
    int cn = min(CH, E - e0);

    for (int i = tid; i < 1024; i += 256) hist[i] = 0;
    __syncthreads();

    unsigned int mycode[16];
    short myb[16], myslot[16];
    #pragma unroll
    for (int j = 0; j < 16; j++) {
        int idx = j * 256 + tid;
        if (idx < cn) {
            int e = e0 + idx;
            int src = ei[e];
            int dst = ei[E + e];
            int b = dst >> 7;
            mycode[j] = (unsigned int)src | ((unsigned int)(dst & 127) << 17);
            myb[j] = (short)b;
            myslot[j] = (short)atomicAdd(&hist[b], 1);
        } else myb[j] = -1;
    }
    __syncthreads();

    int h0 = hist[tid * 4], h1 = hist[tid * 4 + 1], h2 = hist[tid * 4 + 2], h3 = hist[tid * 4 + 3];
    int t4 = h0 + h1 + h2 + h3;
    warr[tid] = t4;
    __syncthreads();
    for (int o = 1; o < 256; o <<= 1) {
        int x = (tid >= o) ? warr[tid - o] : 0;
        __syncthreads();
        warr[tid] += x;
        __syncthreads();
    }
    int ex = warr[tid] - t4;
    base[tid * 4] = ex;
    base[tid * 4 + 1] = ex + h0;
    base[tid * 4 + 2] = ex + h0 + h1;
    base[tid * 4 + 3] = ex + h0 + h1 + h2;
    __syncthreads();

    #pragma unroll
    for (int j = 0; j < 16; j++) {
        if (myb[j] >= 0) {
            int p = base[myb[j]] + myslot[j];
            stage[p] = mycode[j];
            stb[p] = (unsigned short)myb[j];
        }
    }
    for (int b = tid; b < NB; b += 256) {
        int c = hist[b];
        if (c) gbase[b] = atomicAdd(&bcur[b], c);
    }
    __syncthreads();
    for (int i = tid; i < cn; i += 256) {
        int b = stb[i];
        binned[gbase[b] + (i - base[b])] = stage[i];
    }
}

// ---------------- scan per-bucket counts -> global CSR bucket offsets ----------------
__global__ void k_bscan(const int* __restrict__ bcur, int* __restrict__ boff,
                        int* __restrict__ offs) {
    __shared__ int sd[1024];
    int t = threadIdx.x;
    int v = (t < NB) ? (bcur[t] - t * CAP) : 0;
    sd[t] = v;
    __syncthreads();
    for (int o = 1; o < 1024; o <<= 1) {
        int x = (t >= o) ? sd[t - o] : 0;
        __syncthreads();
        sd[t] += x;
        __syncthreads();
    }
    if (t < NB) boff[t] = sd[t] - v;   // exclusive
    if (t == 0) { boff[NB] = N_EDGES; offs[N_NODES] = N_EDGES; }
}

// ---------------- per-bucket: node degrees, dinv, offs, exact CSR scatter ----------------
__global__ __launch_bounds__(256) void k_sortd(const unsigned int* __restrict__ binned,
        const int* __restrict__ bcur, const int* __restrict__ boff,
        int* __restrict__ offs, float* __restrict__ dinv,
        int* __restrict__ csr, int n) {
    __shared__ int hist[128], hsc[128], lcur[128];
    int b = blockIdx.x, t = threadIdx.x;
    int nb0 = b * 128;
    int e0 = b * CAP;
    int cnt = bcur[b] - e0;
    if (t < 128) hist[t] = 0;
    __syncthreads();
    for (int i = t; i < cnt; i += 256)
        atomicAdd(&hist[binned[e0 + i] >> 17], 1);
    __syncthreads();
    int v = (t < 128) ? hist[t] : 0;
    if (t < 128) hsc[t] = v;
    __syncthreads();
    for (int o = 1; o < 128; o <<= 1) {
        int x = (t < 128 && t >= o) ? hsc[t - o] : 0;
        __syncthreads();
        if (t < 128) hsc[t] += x;
        __syncthreads();
    }
    int nr = min(128, n - nb0);
    if (t < nr) {
        int off = boff[b] + hsc[t] - v;   // exclusive within bucket
        offs[nb0 + t] = off;
        lcur[t] = off;
        dinv[nb0 + t] = rsqrtf((float)(v + 1));
    }
    __syncthreads();
    for (int i = t; i < cnt; i += 256) {
        unsigned int code = binned[e0 + i];
        int pos = atomicAdd(&lcur[code >> 17], 1);
        csr[pos] = (int)(code & 0x1FFFF);
    }
}

// ---------------- W f32 -> bf16 ----------------
__global__ void k_wcvt(const float* __restrict__ Wf, unsigned short* __restrict__ Wb) {
    int i = blockIdx.x * 256 + threadIdx.x;
    if (i < 128 * 128) Wb[i] = f2bf(Wf[i]);
}

// ---------------- GEMM h = x @ W^T via bf16 MFMA, h stored as bf16 ----------------
__global__ __launch_bounds__(256) void k_gemm(const float* __restrict__ x,
                                              const unsigned short* __restrict__ Wb,
                                              unsigned short* __restrict__ hb, int n) {
    int w = threadIdx.x >> 6;
    int l = threadIdx.x & 63;
    int rowbase = blockIdx.x * 256 + w * 64;
    int r16 = l & 15;
    int kg = l >> 4;

    short8 a[4][4];
    #pragma unroll
    for (int m = 0; m < 4; m++) {
        int row = rowbase + m * 16 + r16;
        int rca = min(row, n - 1);
        const float* base = x + rca * 128;
        #pragma unroll
        for (int q = 0; q < 4; q++) {
            const float4* xp = (const float4*)(base + q * 32 + kg * 8);
            float4 lo = xp[0], hi = xp[1];
            short8 af;
            af[0] = (short)f2bf(lo.x); af[1] = (short)f2bf(lo.y);
            af[2] = (short)f2bf(lo.z); af[3] = (short)f2bf(lo.w);
            af[4] = (short)f2bf(hi.x); af[5] = (short)f2bf(hi.y);
            af[6] = (short)f2bf(hi.z); af[7] = (short)f2bf(hi.w);
            a[m][q] = af;
        }
    }
    for (int t = 0; t < 8; t++) {
        int col = t * 16 + r16;
        short8 b[4];
        #pragma unroll
        for (int q = 0; q < 4; q++)
            b[q] = *(const short8*)(Wb + col * 128 + q * 32 + kg * 8);

        floatx4 acc[4] = {};
        #pragma unroll
        for (int m = 0; m < 4; m++)
            #pragma unroll
            for (int q = 0; q < 4; q++)
                acc[m] = __builtin_amdgcn_mfma_f32_16x16x32_bf16(a[m][q], b[q], acc[m], 0, 0, 0);

        #pragma unroll
        for (int m = 0; m < 4; m++) {
            #pragma unroll
            for (int r = 0; r < 4; r++) {
                int row = rowbase + m * 16 + kg * 4 + r;
                if (row < n) hb[row * 128 + col] = f2bf(acc[m][r]);
            }
        }
    }
}

// ---------------- aggregation: one wave per node, register accumulation, 8x MLP ----------------
__global__ void k_agg(const unsigned int* __restrict__ hp, const float* __restrict__ dinv,
                      const int* __restrict__ offs, const int* __restrict__ csr,
                      unsigned int* __restrict__ ob, int n) {
    int w = threadIdx.x >> 6;
    int l = threadIdx.x & 63;
    int i = blockIdx.x * 4 + w;
    if (i >= n) return;
    float di = dinv[i];
    unsigned int sv = hp[i * 64 + l];
    float sn = di * di;
    float ax = bflo(sv) * sn;
    float ay = bfhi(sv) * sn;
    int s0 = offs[i];
    int cnt = offs[i + 1] - s0;
    for (int base = 0; base < cnt; base += 64) {
        int rem = min(cnt - base, 64);
        int   myidx = (l < rem) ? csr[s0 + base + l] : 0;
        float mydi  = (l < rem) ? dinv[myidx] : 0.0f;
        int e = 0;
        for (; e + 7 < rem; e += 8) {
            unsigned int hv[8]; float nn[8];
            #pragma unroll
            for (int j = 0; j < 8; j++) {
                int s = __shfl(myidx, e + j);
                nn[j] = di * __shfl(mydi, e + j);
                hv[j] = hp[s * 64 + l];
            }
            #pragma unroll
            for (int j = 0; j < 8; j++) {
                ax += nn[j] * bflo(hv[j]);
                ay += nn[j] * bfhi(hv[j]);
            }
        }
        for (; e < rem; e++) {
            int src = __shfl(myidx, e);
            float nrm = di * __shfl(mydi, e);
            unsigned int hv = hp[src * 64 + l];
            ax += nrm * bflo(hv);
            ay += nrm * bfhi(hv);
        }
    }
    ob[i * 64 + l] = (unsigned int)f2bf(ax) | ((unsigned int)f2bf(ay) << 16);
}

// ---------------- BN stats from bf16 ob ----------------
__global__ void k_stats(const unsigned int* __restrict__ ob, float* __restrict__ sums,
                        float* __restrict__ sumsq, int n) {
    int tid = threadIdx.x;
    int c2 = tid & 63;
    int rh = tid >> 6;  // 0..3
    float s0 = 0, s1 = 0, q0 = 0, q1 = 0;
    for (int r = blockIdx.x * 4 + rh; r < n; r += gridDim.x * 4) {
        unsigned int v = ob[r * 64 + c2];
        float a = bflo(v), b = bfhi(v);
        s0 += a; q0 += a * a;
        s1 += b; q1 += b * b;
    }
    __shared__ float ls[4][128], lq[4][128];
    ls[rh][2 * c2] = s0; ls[rh][2 * c2 + 1] = s1;
    lq[rh][2 * c2] = q0; lq[rh][2 * c2 + 1] = q1;
    __syncthreads();
    if (tid < 128) {
        float s = 0, q = 0;
        #pragma unroll
        for (int j = 0; j < 4; j++) { s += ls[j][tid]; q += lq[j][tid]; }
        atomicAdd(&sums[tid], s);
        atomicAdd(&sumsq[tid], q);
    }
}

// ---------------- BN normalize + ReLU: bf16 ob -> f32 out ----------------
__global__ void k_bn(const unsigned int* __restrict__ ob, float* __restrict__ out,
                     const float* __restrict__ sums, const float* __restrict__ sumsq,
                     const float* __restrict__ gamma, const float* __restrict__ beta, int n) {
    int idx = blockIdx.x * 256 + threadIdx.x;
    if (idx >= n * 64) return;
    int c2 = idx & 63;
    int c0 = 2 * c2, c1 = c0 + 1;
    unsigned int v = ob[idx];
    float invN = 1.0f / (float)n;
    float m0 = sums[c0] * invN, m1 = sums[c1] * invN;
    float sc0 = rsqrtf(sumsq[c0] * invN - m0 * m0 + BN_EPS) * gamma[c0];
    float sc1 = rsqrtf(sumsq[c1] * invN - m1 * m1 + BN_EPS) * gamma[c1];
    float o0 = fmaxf((bflo(v) - m0) * sc0 + beta[c0], 0.0f);
    float o1 = fmaxf((bfhi(v) - m1) * sc1 + beta[c1], 0.0f);
    ((float2*)out)[idx] = make_float2(o0, o1);
}

extern "C" void kernel_launch(void* const* d_in, const int* in_sizes, int n_in,
                              void* d_out, int out_size, void* d_ws, size_t ws_size,
                              hipStream_t stream) {
    const float* x     = (const float*)d_in[0];
    const int*   ei    = (const int*)d_in[1];     // [2][E]
    const float* W     = (const float*)d_in[2];
    // d_in[3] = b : cancels exactly under training-mode BatchNorm -> unused
    const float* gamma = (const float*)d_in[4];
    const float* beta  = (const float*)d_in[5];
    float* out = (float*)d_out;

    const int n = N_NODES, E = N_EDGES;

    // workspace layout (~58.5 MB; ob aliases dead `binned`)
    unsigned short* hb   = (unsigned short*)d_ws;          // 12.8M bf16 (25.6 MB)
    int*   csr    = (int*)(hb + 12800000);                 // 1.6M (6.4 MB)
    float* dinv   = (float*)(csr + N_EDGES);               // 100k
    int*   offs   = (int*)(dinv + 100000);                 // 100001
    float* sums   = (float*)(offs + 100001);               // 128
    float* sumsq  = sums + 128;                            // 128
    unsigned short* Wb = (unsigned short*)(sumsq + 128);   // 16384 bf16
    int*   bcur   = (int*)(Wb + 16384);                    // NB
    int*   boff   = bcur + NB;                             // NB+1
    unsigned int* binned = (unsigned int*)(boff + NB + 1); // NB*CAP (8.4 MB)
    unsigned int* ob = binned;                             // 6.4M u32 (25.6 MB), aliases binned (dead after k_sortd)

    hipMemsetAsync(sums, 0, 256 * sizeof(float), stream);

    k_initb<<<(NB + 255) / 256, 256, 0, stream>>>(bcur);
    k_bin<<<(E + CH - 1) / CH, 256, 0, stream>>>(ei, bcur, binned, E);
    k_bscan<<<1, 1024, 0, stream>>>(bcur, boff, offs);
    k_sortd<<<NB, 256, 0, stream>>>(binned, bcur, boff, offs, dinv, csr, n);

    k_wcvt<<<64, 256, 0, stream>>>(W, Wb);
    k_gemm<<<(n + 255) / 256, 256, 0, stream>>>(x, Wb, hb, n);

    k_agg<<<(n + 3) / 4, 256, 0, stream>>>((const unsigned int*)hb, dinv, offs, csr, ob, n);

    k_stats<<<512, 256, 0, stream>>>(ob, sums, sumsq, n);
    k_bn<<<(n * 64 + 255) / 256, 256, 0, stream>>>(ob, out, sums, sumsq, gamma, beta, n);
}

// Round 6
// 177.314 us; speedup vs baseline: 8.6374x; 1.0945x over previous
//
#include <hip/hip_runtime.h>

#define N_NODES 100000
#define N_EDGES 1600000
#define BN_EPS 1e-5f
#define NB 782        // ceil(100000/128) buckets of 128 nodes
#define CAP 2688      // fixed bucket capacity (mean 2048 + 14 sigma)
#define CH 2048       // edges per binning block

typedef short short8 __attribute__((ext_vector_type(8)));
typedef float floatx4 __attribute__((ext_vector_type(4)));

__device__ __forceinline__ unsigned short f2bf(float f) {
    unsigned int u = __float_as_uint(f);
    unsigned int r = (u + 0x7fffu + ((u >> 16) & 1u)) >> 16;  // RNE
    return (unsigned short)r;
}
__device__ __forceinline__ float bflo(unsigned int v) { return __uint_as_float(v << 16); }
__device__ __forceinline__ float bfhi(unsigned int v) { return __uint_as_float(v & 0xffff0000u); }

// ---------------- LDS-staged binning: edges -> bucket-grouped code words ----------------
// code = src | (local_dst << 17); bucket b's region = [b*CAP, b*CAP + bcnt[b])
__global__ __launch_bounds__(256) void k_bin(const int* __restrict__ ei,
                                             int* __restrict__ bcnt,
                                             unsigned int* __restrict__ binned, int E) {
    __shared__ int hist[1024];
    __shared__ int base[1024];
    __shared__ int gbase[1024];
    __shared__ int warr[256];
    __shared__ unsigned int stage[CH];
    __shared__ unsigned short stb[CH];
    int tid = threadIdx.x;
    int e0 = blockIdx.x * CH;
    int cn = min(CH, E - e0);

    for (int i = tid; i < 1024; i += 256) hist[i] = 0;
    __syncthreads();

    unsigned int mycode[8];
    short myb[8], myslot[8];
    #pragma unroll
    for (int j = 0; j < 8; j++) {
        int idx = j * 256 + tid;
        if (idx < cn) {
            int e = e0 + idx;
            int src = ei[e];
            int dst = ei[E + e];
            int b = dst >> 7;
            mycode[j] = (unsigned int)src | ((unsigned int)(dst & 127) << 17);
            myb[j] = (short)b;
            myslot[j] = (short)atomicAdd(&hist[b], 1);
        } else myb[j] = -1;
    }
    __syncthreads();

    int h0 = hist[tid * 4], h1 = hist[tid * 4 + 1], h2 = hist[tid * 4 + 2], h3 = hist[tid * 4 + 3];
    int t4 = h0 + h1 + h2 + h3;
    warr[tid] = t4;
    __syncthreads();
    for (int o = 1; o < 256; o <<= 1) {
        int x = (tid >= o) ? warr[tid - o] : 0;
        __syncthreads();
        warr[tid] += x;
        __syncthreads();
    }
    int ex = warr[tid] - t4;
    base[tid * 4] = ex;
    base[tid * 4 + 1] = ex + h0;
    base[tid * 4 + 2] = ex + h0 + h1;
    base[tid * 4 + 3] = ex + h0 + h1 + h2;
    __syncthreads();

    #pragma unroll
    for (int j = 0; j < 8; j++) {
        if (myb[j] >= 0) {
            int p = base[myb[j]] + myslot[j];
            stage[p] = mycode[j];
            stb[p] = (unsigned short)myb[j];
        }
    }
    for (int b = tid; b < NB; b += 256) {
        int c = hist[b];
        if (c) gbase[b] = b * CAP + atomicAdd(&bcnt[b], c);
    }
    __syncthreads();
    for (int i = tid; i < cn; i += 256) {
        int b = stb[i];
        binned[gbase[b] + (i - base[b])] = stage[i];
    }
}

// ---------------- per-bucket degree histogram -> dinv ----------------
__global__ __launch_bounds__(256) void k_dd(const unsigned int* __restrict__ binned,
                                            const int* __restrict__ bcnt,
                                            float* __restrict__ dinv, int n) {
    __shared__ int hist[128];
    int b = blockIdx.x, t = threadIdx.x;
    int nb0 = b * 128;
    int e0 = b * CAP;
    int cnt = bcnt[b];
    if (t < 128) hist[t] = 0;
    __syncthreads();
    for (int i = t; i < cnt; i += 256)
        atomicAdd(&hist[binned[e0 + i] >> 17], 1);
    __syncthreads();
    int nr = min(128, n - nb0);
    if (t < nr) dinv[nb0 + t] = rsqrtf((float)(hist[t] + 1));
}

// ---------------- W f32 -> bf16 ----------------
__global__ void k_wcvt(const float* __restrict__ Wf, unsigned short* __restrict__ Wb) {
    int i = blockIdx.x * 256 + threadIdx.x;
    if (i < 128 * 128) Wb[i] = f2bf(Wf[i]);
}

// ---------------- GEMM h = x @ W^T via bf16 MFMA, h stored as bf16 ----------------
__global__ __launch_bounds__(256) void k_gemm(const float* __restrict__ x,
                                              const unsigned short* __restrict__ Wb,
                                              unsigned short* __restrict__ hb, int n) {
    int w = threadIdx.x >> 6;
    int l = threadIdx.x & 63;
    int rowbase = blockIdx.x * 256 + w * 64;
    int r16 = l & 15;
    int kg = l >> 4;

    short8 a[4][4];
    #pragma unroll
    for (int m = 0; m < 4; m++) {
        int row = rowbase + m * 16 + r16;
        int rca = min(row, n - 1);
        const float* base = x + rca * 128;
        #pragma unroll
        for (int q = 0; q < 4; q++) {
            const float4* xp = (const float4*)(base + q * 32 + kg * 8);
            float4 lo = xp[0], hi = xp[1];
            short8 af;
            af[0] = (short)f2bf(lo.x); af[1] = (short)f2bf(lo.y);
            af[2] = (short)f2bf(lo.z); af[3] = (short)f2bf(lo.w);
            af[4] = (short)f2bf(hi.x); af[5] = (short)f2bf(hi.y);
            af[6] = (short)f2bf(hi.z); af[7] = (short)f2bf(hi.w);
            a[m][q] = af;
        }
    }
    for (int t = 0; t < 8; t++) {
        int col = t * 16 + r16;
        short8 b[4];
        #pragma unroll
        for (int q = 0; q < 4; q++)
            b[q] = *(const short8*)(Wb + col * 128 + q * 32 + kg * 8);

        floatx4 acc[4] = {};
        #pragma unroll
        for (int m = 0; m < 4; m++)
            #pragma unroll
            for (int q = 0; q < 4; q++)
                acc[m] = __builtin_amdgcn_mfma_f32_16x16x32_bf16(a[m][q], b[q], acc[m], 0, 0, 0);

        #pragma unroll
        for (int m = 0; m < 4; m++) {
            #pragma unroll
            for (int r = 0; r < 4; r++) {
                int row = rowbase + m * 16 + kg * 4 + r;
                if (row < n) hb[row * 128 + col] = f2bf(acc[m][r]);
            }
        }
    }
}

// ---------------- fused: per-bucket LDS sort + wave-per-node aggregation + BN stats ----------------
__global__ __launch_bounds__(512) void k_fused(const unsigned int* __restrict__ hp,
        const float* __restrict__ dinv, const int* __restrict__ bcnt,
        const unsigned int* __restrict__ binned, float* __restrict__ out,
        float* __restrict__ sums, float* __restrict__ sumsq, int n) {
    __shared__ int hist[128], hsc[128];
    __shared__ float dl[128];
    __shared__ int sh_src[CAP];
    __shared__ float sh_nrm[CAP];
    __shared__ float ps[8][128], pq[8][128];
    int t = threadIdx.x;
    int w = t >> 6, l = t & 63;
    int b = blockIdx.x;
    int nb0 = b * 128;
    int e0 = b * CAP;
    int cnt = bcnt[b];
    int nr = min(128, n - nb0);

    if (t < 128) {
        hist[t] = 0;
        if (t < nr) dl[t] = dinv[nb0 + t];
    }
    __syncthreads();

    // round 1: count + claim slot
    unsigned int mycode[6];
    short myslot[6];
    #pragma unroll
    for (int j = 0; j < 6; j++) {
        int i = j * 512 + t;
        if (i < cnt) {
            unsigned int code = binned[e0 + i];
            mycode[j] = code;
            myslot[j] = (short)atomicAdd(&hist[code >> 17], 1);
        } else myslot[j] = -1;
    }
    __syncthreads();

    // inclusive scan of hist[128]
    int v = (t < 128) ? hist[t] : 0;
    if (t < 128) hsc[t] = v;
    __syncthreads();
    for (int o = 1; o < 128; o <<= 1) {
        int x = (t < 128 && t >= o) ? hsc[t - o] : 0;
        __syncthreads();
        if (t < 128) hsc[t] += x;
        __syncthreads();
    }

    // place: sorted edge lists + precomputed norm in LDS
    #pragma unroll
    for (int j = 0; j < 6; j++) {
        if (myslot[j] >= 0) {
            unsigned int code = mycode[j];
            int ld = code >> 17;
            int src = code & 0x1FFFF;
            int pos = hsc[ld] - hist[ld] + myslot[j];
            sh_src[pos] = src;
            sh_nrm[pos] = dinv[src] * dl[ld];
        }
    }
    __syncthreads();

    // aggregation: wave w handles nodes w, w+8, ... ; register accumulate, 8-deep MLP
    float s0 = 0, s1 = 0, q0 = 0, q1 = 0;
    for (int r = w; r < nr; r += 8) {
        int i = nb0 + r;
        float di = dl[r];
        unsigned int sv = hp[i * 64 + l];
        float sn = di * di;
        float ax = bflo(sv) * sn;
        float ay = bfhi(sv) * sn;
        int off = hsc[r] - hist[r];
        int dg = hist[r];
        int e = 0;
        for (; e + 7 < dg; e += 8) {
            unsigned int hv[8]; float nn[8];
            #pragma unroll
            for (int j = 0; j < 8; j++) {
                int s = sh_src[off + e + j];
                nn[j] = sh_nrm[off + e + j];
                hv[j] = hp[s * 64 + l];
            }
            #pragma unroll
            for (int j = 0; j < 8; j++) {
                ax += nn[j] * bflo(hv[j]);
                ay += nn[j] * bfhi(hv[j]);
            }
        }
        for (; e < dg; e++) {
            int s = sh_src[off + e];
            float nnm = sh_nrm[off + e];
            unsigned int hv = hp[s * 64 + l];
            ax += nnm * bflo(hv);
            ay += nnm * bfhi(hv);
        }
        ((float2*)out)[i * 64 + l] = make_float2(ax, ay);
        s0 += ax; q0 += ax * ax;
        s1 += ay; q1 += ay * ay;
    }

    // BN partial stats: thread covers cols (2l, 2l+1)
    ps[w][2 * l] = s0; ps[w][2 * l + 1] = s1;
    pq[w][2 * l] = q0; pq[w][2 * l + 1] = q1;
    __syncthreads();
    if (t < 128) {
        float s = 0, q = 0;
        #pragma unroll
        for (int j = 0; j < 8; j++) { s += ps[j][t]; q += pq[j][t]; }
        atomicAdd(&sums[t], s);
        atomicAdd(&sumsq[t], q);
    }
}

// ---------------- BN normalize + ReLU (in place on f32 out) ----------------
__global__ void k_bn(float* __restrict__ out, const float* __restrict__ sums,
                     const float* __restrict__ sumsq, const float* __restrict__ gamma,
                     const float* __restrict__ beta, int n) {
    int idx = blockIdx.x * 256 + threadIdx.x;
    int total = n * 32;
    if (idx >= total) return;
    int c0 = (idx & 31) * 4;
    float invN = 1.0f / (float)n;
    float4 v = ((const float4*)out)[idx];
    float r[4] = {v.x, v.y, v.z, v.w};
    #pragma unroll
    for (int j = 0; j < 4; j++) {
        int c = c0 + j;
        float mean = sums[c] * invN;
        float var = sumsq[c] * invN - mean * mean;
        float scale = rsqrtf(var + BN_EPS) * gamma[c];
        float o = (r[j] - mean) * scale + beta[c];
        r[j] = fmaxf(o, 0.0f);
    }
    ((float4*)out)[idx] = make_float4(r[0], r[1], r[2], r[3]);
}

extern "C" void kernel_launch(void* const* d_in, const int* in_sizes, int n_in,
                              void* d_out, int out_size, void* d_ws, size_t ws_size,
                              hipStream_t stream) {
    const float* x     = (const float*)d_in[0];
    const int*   ei    = (const int*)d_in[1];     // [2][E]
    const float* W     = (const float*)d_in[2];
    // d_in[3] = b : cancels exactly under training-mode BatchNorm -> unused
    const float* gamma = (const float*)d_in[4];
    const float* beta  = (const float*)d_in[5];
    float* out = (float*)d_out;

    const int n = N_NODES, E = N_EDGES;

    // workspace layout (~34.6 MB)
    unsigned short* hb   = (unsigned short*)d_ws;          // 12.8M bf16 (25.6 MB)
    float* dinv   = (float*)(hb + 12800000);               // 100k f32
    float* sums   = dinv + 100000;                         // 128  (memset region start)
    float* sumsq  = sums + 128;                            // 128
    int*   bcnt   = (int*)(sumsq + 128);                   // NB   (memset region end)
    unsigned short* Wb = (unsigned short*)(bcnt + NB);     // 16384 bf16
    unsigned int* binned = (unsigned int*)(Wb + 16384);    // NB*CAP u32 (8.4 MB)

    hipMemsetAsync(sums, 0, (256 + NB) * sizeof(int), stream);

    k_bin<<<(E + CH - 1) / CH, 256, 0, stream>>>(ei, bcnt, binned, E);
    k_dd<<<NB, 256, 0, stream>>>(binned, bcnt, dinv, n);

    k_wcvt<<<64, 256, 0, stream>>>(W, Wb);
    k_gemm<<<(n + 255) / 256, 256, 0, stream>>>(x, Wb, hb, n);

    k_fused<<<NB, 512, 0, stream>>>((const unsigned int*)hb, dinv, bcnt, binned,
                                    out, sums, sumsq, n);

    k_bn<<<(n * 32 + 255) / 256, 256, 0, stream>>>(out, sums, sumsq, gamma, beta, n);
}